// Round 6
// baseline (468.443 us; speedup 1.0000x reference)
//
#include <hip/hip_runtime.h>
#include <hip/hip_bf16.h>

#define E_EDGES 800000
#define NNODES  50000
#define HID     128

typedef __bf16 bf16x8 __attribute__((ext_vector_type(8)));
typedef float  f32x4  __attribute__((ext_vector_type(4)));
typedef unsigned short ushortx8 __attribute__((ext_vector_type(8)));

__device__ __forceinline__ unsigned short f2bf(float f) {   // RTNE
    union { float f; unsigned u; } v; v.f = f;
    unsigned r = v.u + 0x7FFFu + ((v.u >> 16) & 1u);
    return (unsigned short)(r >> 16);
}
__device__ __forceinline__ unsigned short f2bf_fast(float f) { // round-half-up
    union { float f; unsigned u; } v; v.f = f;
    return (unsigned short)((v.u + 0x8000u) >> 16);
}
__device__ __forceinline__ float bf2f(unsigned short u) {
    union { unsigned u; float f; } v; v.u = ((unsigned)u) << 16;
    return v.f;
}
// silu without IEEE-divide expansion: mul, exp, add, rcp, mul
__device__ __forceinline__ float silu_fast(float x) {
    float e = __expf(-x);
    return x * __builtin_amdgcn_rcpf(1.0f + e);
}

// ============ fast path: node projection + fused prep ============
// grid (586, 3):
//   y==0/1 (x<391): P/Q GEMM halves; W1 B-frags self-packed into LDS.
//   y==2: out:=coord (150000) + pack W2p/W3b2/Eea for edge kernel.
// PQb[node][p]: p<128 = P (h@W1a^T+b1), p>=128 = Q (h@W1b^T); sigma-permuted
// feature order (position p holds channel (p&7)*16+(p>>3)).
__launch_bounds__(256)
__global__ void node_gemm(const float* __restrict__ h,
                          const float* __restrict__ W1, const float* __restrict__ b1,
                          const float* __restrict__ W2, const float* __restrict__ b2,
                          const float* __restrict__ W3,
                          const float* __restrict__ coord, float* __restrict__ out,
                          unsigned short* __restrict__ W2p,
                          float2* __restrict__ W3b2, float2* __restrict__ Eea,
                          unsigned short* __restrict__ PQb) {
    if (blockIdx.y == 2) {
        int i = blockIdx.x * 256 + threadIdx.x;   // < 150016
        if (i < 3 * NNODES) out[i] = coord[i];
        if (i < 16384) {
            int j = i & 7, lane = (i >> 3) & 63, nt = (i >> 9) & 7, kc = i >> 12;
            int n = lane & 15, quad = lane >> 4;
            int p = kc * 32 + quad * 8 + j;
            int f = (p & 7) * 16 + (p >> 3);
            W2p[i] = f2bf(W2[(nt * 16 + n) * 128 + f]);
        } else if (i < 16512) {
            int c = i - 16384;
            W3b2[c] = make_float2(W3[c], b2[c]);
        } else if (i < 16640) {
            int p = i - 16512;
            int f = (p & 7) * 16 + (p >> 3);
            Eea[p] = make_float2(W1[f * 258 + 256], W1[f * 258 + 257]);
        }
        return;
    }
    if (blockIdx.x >= 391) return;

    __shared__ __align__(16) unsigned short W1s[16384];  // 32 KB: this half's B-frags
    const int half = blockIdx.y;               // 0 = P (W1a + b1), 1 = Q (W1b)
    const int w    = threadIdx.x >> 6;
    const int lane = threadIdx.x & 63;
    const int n    = lane & 15;
    const int quad = lane >> 4;
    const int base = (blockIdx.x * 4 + w) * 32;

    // cooperative pack: W1s[((kc*8+nt)*64+l)*8+j] = W1[(nt*16+(l&15)) , (half*4+kc)*32+(l>>4)*8+j]
    for (int t = threadIdx.x; t < 16384; t += 256) {
        int j = t & 7, l = (t >> 3) & 63, nt = (t >> 9) & 7, kc = t >> 12;
        int nn = l & 15, qq = l >> 4;
        int k = (half * 4 + kc) * 32 + qq * 8 + j;
        W1s[t] = f2bf(W1[(nt * 16 + nn) * 258 + k]);
    }
    __syncthreads();

    int nodeA[2];
#pragma unroll
    for (int mt = 0; mt < 2; ++mt) {
        int nd = base + mt * 16 + n;
        nodeA[mt] = nd < NNODES ? nd : NNODES - 1;
    }

    const f32x4 zero = { 0.f, 0.f, 0.f, 0.f };
    f32x4 acc[2][8];
#pragma unroll
    for (int mt = 0; mt < 2; ++mt)
#pragma unroll
        for (int nt = 0; nt < 8; ++nt) acc[mt][nt] = zero;

#pragma unroll
    for (int kc = 0; kc < 4; ++kc) {
        bf16x8 af[2];
#pragma unroll
        for (int mt = 0; mt < 2; ++mt) {
            const float* p = h + (long)nodeA[mt] * HID + kc * 32 + quad * 8;
            float4 lo = *(const float4*)p;
            float4 hi = *(const float4*)(p + 4);
            ushortx8 u;
            u[0] = f2bf(lo.x); u[1] = f2bf(lo.y); u[2] = f2bf(lo.z); u[3] = f2bf(lo.w);
            u[4] = f2bf(hi.x); u[5] = f2bf(hi.y); u[6] = f2bf(hi.z); u[7] = f2bf(hi.w);
            af[mt] = __builtin_bit_cast(bf16x8, u);
        }
#pragma unroll
        for (int nt = 0; nt < 8; ++nt) {
            bf16x8 bf = __builtin_bit_cast(bf16x8, *(const ushortx8*)&W1s[((kc * 8 + nt) * 64 + lane) * 8]);
            acc[0][nt] = __builtin_amdgcn_mfma_f32_16x16x32_bf16(af[0], bf, acc[0][nt], 0, 0, 0);
            acc[1][nt] = __builtin_amdgcn_mfma_f32_16x16x32_bf16(af[1], bf, acc[1][nt], 0, 0, 0);
        }
    }

    float b1v[8];
#pragma unroll
    for (int nt = 0; nt < 8; ++nt) b1v[nt] = (half == 0) ? b1[nt * 16 + n] : 0.f;

#pragma unroll
    for (int mt = 0; mt < 2; ++mt) {
#pragma unroll
        for (int r = 0; r < 4; ++r) {
            int node = base + mt * 16 + quad * 4 + r;
            if (node < NNODES) {
                ushortx8 u;
#pragma unroll
                for (int nt = 0; nt < 8; ++nt)
                    u[nt] = f2bf(acc[mt][nt][r] + b1v[nt]);   // stored at p = n*8+nt
                *(ushortx8*)(PQb + (long)node * 256 + half * 128 + n * 8) = u;
            }
        }
    }
}

// ============ fast path: pipelined edge kernel ============
// T=4 tiles of 16 edges per wave, depth-2 software pipeline:
// while computing tile t, PQ gathers for t+1 and indices for t+2 are in flight.
__launch_bounds__(256, 4)
__global__ void edge16p(const unsigned short* __restrict__ PQb,
                        const int* __restrict__ ei,
                        const float* __restrict__ cdiff,
                        const float2* __restrict__ eattr,
                        const ushortx8* __restrict__ W2p,
                        const float4* __restrict__ Eea4,
                        const float2* __restrict__ W3b2,
                        float* __restrict__ out) {
    constexpr int T = 4;
    const int lane = threadIdx.x & 63;
    const int n    = lane & 15;
    const int quad = lane >> 4;
    const int base = ((blockIdx.x * 4) + (threadIdx.x >> 6)) * (16 * T);

    int ri[T], ci[T];
    float2 ea[T];
    ushortx8 pf[2][4], qf[2][4];

    auto loadIdx = [&](int t) {
        int el = base + t * 16 + n;
        ri[t] = ei[el];
        ci[t] = ei[E_EDGES + el];
        ea[t] = eattr[el];
    };
    auto loadPQ = [&](int t) {
        const unsigned short* Pb = PQb + (long)ri[t] * 256 + quad * 8;
        const unsigned short* Qb = PQb + (long)ci[t] * 256 + 128 + quad * 8;
        const int b = t & 1;
#pragma unroll
        for (int kc = 0; kc < 4; ++kc) {
            pf[b][kc] = *(const ushortx8*)(Pb + kc * 32);
            qf[b][kc] = *(const ushortx8*)(Qb + kc * 32);
        }
    };

    loadIdx(0);
    loadPQ(0);
    loadIdx(1);

#pragma unroll
    for (int t = 0; t < T; ++t) {
        if (t + 1 < T) loadPQ(t + 1);
        if (t + 2 < T) loadIdx(t + 2);
        // ALU/MFMA may cross, VMEM may not: keep prefetches above compute.
        __builtin_amdgcn_sched_barrier(0x9);

        // prefetch this tile's cdiff (independent of everything else)
        float c0 = 0.f, c1 = 0.f, c2 = 0.f;
        if (lane < 16) {
            long e2 = base + t * 16 + lane;
            c0 = cdiff[3 * e2 + 0];
            c1 = cdiff[3 * e2 + 1];
            c2 = cdiff[3 * e2 + 2];
        }

        const int b = t & 1;
        ushortx8 u[4];
#pragma unroll
        for (int kc = 0; kc < 4; ++kc) {
            float4 ef[4];
#pragma unroll
            for (int q2 = 0; q2 < 4; ++q2) ef[q2] = Eea4[kc * 16 + quad * 4 + q2];
#pragma unroll
            for (int j = 0; j < 8; ++j) {
                float ex = (j & 1) ? ef[j >> 1].z : ef[j >> 1].x;
                float ey = (j & 1) ? ef[j >> 1].w : ef[j >> 1].y;
                float v = bf2f(pf[b][kc][j]) + bf2f(qf[b][kc][j]) + ea[t].x * ex + ea[t].y * ey;
                u[kc][j] = f2bf_fast(silu_fast(v));
            }
        }

        const f32x4 zero = { 0.f, 0.f, 0.f, 0.f };
        f32x4 acc[8];
#pragma unroll
        for (int nt = 0; nt < 8; ++nt) acc[nt] = zero;
#pragma unroll
        for (int kc = 0; kc < 4; ++kc) {
            bf16x8 af = __builtin_bit_cast(bf16x8, u[kc]);
#pragma unroll
            for (int nt = 0; nt < 8; ++nt) {
                bf16x8 bf = __builtin_bit_cast(bf16x8, W2p[(kc * 8 + nt) * 64 + lane]);
                acc[nt] = __builtin_amdgcn_mfma_f32_16x16x32_bf16(af, bf, acc[nt], 0, 0, 0);
            }
        }

        // layer 3: silu(acc + b2) . W3, butterfly over n
        float part[4] = { 0.f, 0.f, 0.f, 0.f };
#pragma unroll
        for (int nt = 0; nt < 8; ++nt) {
            float2 wb = W3b2[nt * 16 + n];   // {W3, b2}
#pragma unroll
            for (int r = 0; r < 4; ++r)
                part[r] += silu_fast(acc[nt][r] + wb.y) * wb.x;
        }
#pragma unroll
        for (int mask = 1; mask < 16; mask <<= 1)
#pragma unroll
            for (int r = 0; r < 4; ++r)
                part[r] += __shfl_xor(part[r], mask, 64);

        // lane l<16 takes part[l&3] from lane (l>>2)*16
        float s = 0.f;
#pragma unroll
        for (int r = 0; r < 4; ++r) {
            float t2 = __shfl(part[r], ((lane & 15) >> 2) * 16, 64);
            if ((lane & 3) == r) s = t2;
        }

        if (lane < 16) {
            float ex2 = __expf(2.0f * s);
            float tt = (1.0f - 2.0f * __builtin_amdgcn_rcpf(ex2 + 1.0f)) * 0.15f; // tanh*0.15
            int r = ri[t];   // lane<16: n == lane
            atomicAdd(&out[r * 3 + 0], c0 * tt);
            atomicAdd(&out[r * 3 + 1], c1 * tt);
            atomicAdd(&out[r * 3 + 2], c2 * tt);
        }
    }
}

// ============ fallback path (ws too small): round-5 validated kernels ============
__global__ void prep(const float* __restrict__ W1, const float* __restrict__ b1,
                     const float* __restrict__ W2, const float* __restrict__ b2,
                     const float* __restrict__ W3,
                     const float* __restrict__ coord, float* __restrict__ out,
                     unsigned short* __restrict__ W1p, unsigned short* __restrict__ W2p,
                     float4* __restrict__ Wext, float2* __restrict__ W3b2,
                     float2* __restrict__ Eea) {
    int i = blockIdx.x * 256 + threadIdx.x;
    if (i < 3 * NNODES) out[i] = coord[i];
    if (i < 32768) {
        int j = i & 7, lane = (i >> 3) & 63, nt = (i >> 9) & 7, kc = i >> 12;
        int n = lane & 15, quad = lane >> 4;
        int k = kc * 32 + quad * 8 + j;
        W1p[i] = f2bf(W1[(nt * 16 + n) * 258 + k]);
    } else if (i < 49152) {
        int t = i - 32768;
        int j = t & 7, lane = (t >> 3) & 63, nt = (t >> 9) & 7, kc = t >> 12;
        int n = lane & 15, quad = lane >> 4;
        int p = kc * 32 + quad * 8 + j;
        int f = (p & 7) * 16 + (p >> 3);
        W2p[t] = f2bf(W2[(nt * 16 + n) * 128 + f]);
    } else if (i < 49280) {
        int c = i - 49152;
        Wext[c] = make_float4(W1[c * 258 + 256], W1[c * 258 + 257], b1[c], b2[c]);
    } else if (i < 49408) {
        int c = i - 49280;
        W3b2[c] = make_float2(W3[c], b2[c]);
    } else if (i < 49536) {
        int p = i - 49408;
        int f = (p & 7) * 16 + (p >> 3);
        Eea[p] = make_float2(W1[f * 258 + 256], W1[f * 258 + 257]);
    }
}

__launch_bounds__(256)
__global__ void edge_fb(const float* __restrict__ h, const int* __restrict__ ei,
                        const float* __restrict__ cdiff, const float* __restrict__ eattr,
                        const ushortx8* __restrict__ W1p, const ushortx8* __restrict__ W2p,
                        const float4* __restrict__ Wext, const float* __restrict__ W3,
                        float* __restrict__ out) {
    __shared__ __align__(16) unsigned short x1[4][32][136];
    __shared__ int   rowi[4][32];
    __shared__ int   coli[4][32];
    __shared__ float ea0[4][32];
    __shared__ float ea1[4][32];
    __shared__ float sbuf[4][32];

    const int w = threadIdx.x >> 6, lane = threadIdx.x & 63;
    const int n = lane & 15, quad = lane >> 4;
    const int ebase = (blockIdx.x * 4 + w) * 32;

    if (lane < 32) {
        int e = ebase + lane;
        rowi[w][lane] = ei[e];
        coli[w][lane] = ei[E_EDGES + e];
        const float2 ea = *(const float2*)(eattr + 2 * (long)e);
        ea0[w][lane] = ea.x; ea1[w][lane] = ea.y;
    }
    __syncthreads();

    int nodeR[2] = { rowi[w][n], rowi[w][16 + n] };
    int nodeC[2] = { coli[w][n], coli[w][16 + n] };

    const f32x4 zero = { 0.f, 0.f, 0.f, 0.f };
    f32x4 acc[2][8];
#pragma unroll
    for (int mt = 0; mt < 2; ++mt)
#pragma unroll
        for (int nt = 0; nt < 8; ++nt) acc[mt][nt] = zero;

#pragma unroll
    for (int kc = 0; kc < 8; ++kc) {
        bf16x8 afrag[2];
#pragma unroll
        for (int mt = 0; mt < 2; ++mt) {
            int node = (kc < 4) ? nodeR[mt] : nodeC[mt];
            const float* p = h + (long)node * HID + (kc & 3) * 32 + quad * 8;
            float4 lo = *(const float4*)p;
            float4 hi = *(const float4*)(p + 4);
            ushortx8 u;
            u[0] = f2bf(lo.x); u[1] = f2bf(lo.y); u[2] = f2bf(lo.z); u[3] = f2bf(lo.w);
            u[4] = f2bf(hi.x); u[5] = f2bf(hi.y); u[6] = f2bf(hi.z); u[7] = f2bf(hi.w);
            afrag[mt] = __builtin_bit_cast(bf16x8, u);
        }
#pragma unroll
        for (int nt = 0; nt < 8; ++nt) {
            bf16x8 bfrag = __builtin_bit_cast(bf16x8, W1p[(kc * 8 + nt) * 64 + lane]);
            acc[0][nt] = __builtin_amdgcn_mfma_f32_16x16x32_bf16(afrag[0], bfrag, acc[0][nt], 0, 0, 0);
            acc[1][nt] = __builtin_amdgcn_mfma_f32_16x16x32_bf16(afrag[1], bfrag, acc[1][nt], 0, 0, 0);
        }
    }

    float b2v[8];
    {
        float4 wx[8];
#pragma unroll
        for (int nt = 0; nt < 8; ++nt) wx[nt] = Wext[nt * 16 + n];
#pragma unroll
        for (int nt = 0; nt < 8; ++nt) b2v[nt] = wx[nt].w;
#pragma unroll
        for (int mt = 0; mt < 2; ++mt) {
#pragma unroll
            for (int r = 0; r < 4; ++r) {
                int m = mt * 16 + quad * 4 + r;
                float a0 = ea0[w][m], a1 = ea1[w][m];
                ushortx8 u;
#pragma unroll
                for (int nt = 0; nt < 8; ++nt) {
                    float v = acc[mt][nt][r] + wx[nt].z + a0 * wx[nt].x + a1 * wx[nt].y;
                    u[nt] = f2bf(silu_fast(v));
                }
                *(ushortx8*)&x1[w][m][n * 8] = u;
            }
        }
    }
    __syncthreads();

#pragma unroll
    for (int mt = 0; mt < 2; ++mt)
#pragma unroll
        for (int nt = 0; nt < 8; ++nt) acc[mt][nt] = zero;

#pragma unroll
    for (int kc = 0; kc < 4; ++kc) {
        bf16x8 afrag[2];
#pragma unroll
        for (int mt = 0; mt < 2; ++mt)
            afrag[mt] = __builtin_bit_cast(bf16x8, *(const ushortx8*)&x1[w][mt * 16 + n][kc * 32 + quad * 8]);
#pragma unroll
        for (int nt = 0; nt < 8; ++nt) {
            bf16x8 bfrag = __builtin_bit_cast(bf16x8, W2p[(kc * 8 + nt) * 64 + lane]);
            acc[0][nt] = __builtin_amdgcn_mfma_f32_16x16x32_bf16(afrag[0], bfrag, acc[0][nt], 0, 0, 0);
            acc[1][nt] = __builtin_amdgcn_mfma_f32_16x16x32_bf16(afrag[1], bfrag, acc[1][nt], 0, 0, 0);
        }
    }

    float part[2][4] = { {0.f,0.f,0.f,0.f}, {0.f,0.f,0.f,0.f} };
#pragma unroll
    for (int nt = 0; nt < 8; ++nt) {
        float w3 = W3[nt * 16 + n];
#pragma unroll
        for (int mt = 0; mt < 2; ++mt)
#pragma unroll
            for (int r = 0; r < 4; ++r)
                part[mt][r] += silu_fast(acc[mt][nt][r] + b2v[nt]) * w3;
    }
#pragma unroll
    for (int mask = 1; mask < 16; mask <<= 1)
#pragma unroll
        for (int mt = 0; mt < 2; ++mt)
#pragma unroll
            for (int r = 0; r < 4; ++r)
                part[mt][r] += __shfl_xor(part[mt][r], mask, 64);

    if (n == 0) {
#pragma unroll
        for (int mt = 0; mt < 2; ++mt)
#pragma unroll
            for (int r = 0; r < 4; ++r)
                sbuf[w][mt * 16 + quad * 4 + r] = part[mt][r];
    }
    __syncthreads();

    if (lane < 32) {
        int e = ebase + lane;
        float s = sbuf[w][lane];
        float ex = __expf(2.0f * s);
        float t = (1.0f - 2.0f * __builtin_amdgcn_rcpf(ex + 1.0f)) * 0.15f;
        float c0 = cdiff[3 * (long)e + 0];
        float c1 = cdiff[3 * (long)e + 1];
        float c2 = cdiff[3 * (long)e + 2];
        int r = rowi[w][lane];
        atomicAdd(&out[r * 3 + 0], c0 * t);
        atomicAdd(&out[r * 3 + 1], c1 * t);
        atomicAdd(&out[r * 3 + 2], c2 * t);
    }
}

extern "C" void kernel_launch(void* const* d_in, const int* in_sizes, int n_in,
                              void* d_out, int out_size, void* d_ws, size_t ws_size,
                              hipStream_t stream) {
    const float* h     = (const float*)d_in[0];
    const float* coord = (const float*)d_in[1];
    const int*   ei    = (const int*)d_in[2];
    const float* cdiff = (const float*)d_in[3];
    const float* eattr = (const float*)d_in[4];
    const float* W1    = (const float*)d_in[5];
    const float* b1    = (const float*)d_in[6];
    const float* W2    = (const float*)d_in[7];
    const float* b2    = (const float*)d_in[8];
    const float* W3    = (const float*)d_in[9];
    float* out = (float*)d_out;

    char* ws = (char*)d_ws;
    unsigned short* W1p  = (unsigned short*)ws;                  // 65536 B (fallback only)
    unsigned short* W2p  = (unsigned short*)(ws + 65536);        // 32768 B
    float4*         Wext = (float4*)(ws + 98304);                // 2048 B (fallback only)
    float2*         W3b2 = (float2*)(ws + 100352);               // 1024 B
    float2*         Eea  = (float2*)(ws + 101376);               // 1024 B
    unsigned short* PQb  = (unsigned short*)(ws + 102400);       // 25.6 MB
    const size_t need_full = 102400ull + 25600000ull;

    if (ws_size >= need_full) {
        dim3 ngrid(586, 3);   // y<2: GEMM halves (x<391); y==2: prep slice
        node_gemm<<<ngrid, 256, 0, stream>>>(h, W1, b1, W2, b2, W3, coord, out,
                                             W2p, W3b2, Eea, PQb);
        edge16p<<<E_EDGES / 256, 256, 0, stream>>>(PQb, ei, cdiff, (const float2*)eattr,
                                                   (const ushortx8*)W2p, (const float4*)Eea,
                                                   (const float2*)W3b2, out);
    } else {
        prep<<<(3 * NNODES + 255) / 256, 256, 0, stream>>>(W1, b1, W2, b2, W3, coord, out,
                                                           W1p, W2p, Wext, W3b2, Eea);
        edge_fb<<<E_EDGES / 128, 256, 0, stream>>>(h, ei, cdiff, eattr,
                                                   (const ushortx8*)W1p, (const ushortx8*)W2p,
                                                   (const float4*)Wext, W3, out);
    }
}

// Round 7
// 282.676 us; speedup vs baseline: 1.6572x; 1.6572x over previous
//
#include <hip/hip_runtime.h>
#include <hip/hip_bf16.h>

#define E_EDGES 800000
#define NNODES  50000
#define HID     128

typedef __bf16 bf16x8 __attribute__((ext_vector_type(8)));
typedef float  f32x4  __attribute__((ext_vector_type(4)));
typedef unsigned short ushortx8 __attribute__((ext_vector_type(8)));

__device__ __forceinline__ unsigned short f2bf(float f) {   // RTNE
    union { float f; unsigned u; } v; v.f = f;
    unsigned r = v.u + 0x7FFFu + ((v.u >> 16) & 1u);
    return (unsigned short)(r >> 16);
}
__device__ __forceinline__ unsigned short f2bf_fast(float f) { // round-half-up
    union { float f; unsigned u; } v; v.f = f;
    return (unsigned short)((v.u + 0x8000u) >> 16);
}
__device__ __forceinline__ float bf2f(unsigned short u) {
    union { unsigned u; float f; } v; v.u = ((unsigned)u) << 16;
    return v.f;
}
// silu without IEEE-divide expansion: mul, exp, add, rcp, mul
__device__ __forceinline__ float silu_fast(float x) {
    float e = __expf(-x);
    return x * __builtin_amdgcn_rcpf(1.0f + e);
}

// ---- prep: weight packing + out:=coord (round-5 validated) ----
__global__ void prep(const float* __restrict__ W1, const float* __restrict__ b1,
                     const float* __restrict__ W2, const float* __restrict__ b2,
                     const float* __restrict__ W3,
                     const float* __restrict__ coord, float* __restrict__ out,
                     unsigned short* __restrict__ W1p, unsigned short* __restrict__ W2p,
                     float4* __restrict__ Wext, float2* __restrict__ W3b2,
                     float2* __restrict__ Eea) {
    int i = blockIdx.x * 256 + threadIdx.x;
    if (i < 3 * NNODES) out[i] = coord[i];
    if (i < 32768) {
        int j = i & 7, lane = (i >> 3) & 63, nt = (i >> 9) & 7, kc = i >> 12;
        int n = lane & 15, quad = lane >> 4;
        int k = kc * 32 + quad * 8 + j;
        W1p[i] = f2bf(W1[(nt * 16 + n) * 258 + k]);
    } else if (i < 49152) {
        int t = i - 32768;
        int j = t & 7, lane = (t >> 3) & 63, nt = (t >> 9) & 7, kc = t >> 12;
        int n = lane & 15, quad = lane >> 4;
        int p = kc * 32 + quad * 8 + j;
        int f = (p & 7) * 16 + (p >> 3);
        W2p[t] = f2bf(W2[(nt * 16 + n) * 128 + f]);
    } else if (i < 49280) {
        int c = i - 49152;
        Wext[c] = make_float4(W1[c * 258 + 256], W1[c * 258 + 257], b1[c], b2[c]);
    } else if (i < 49408) {
        int c = i - 49280;
        W3b2[c] = make_float2(W3[c], b2[c]);
    } else if (i < 49536) {
        int p = i - 49408;
        int f = (p & 7) * 16 + (p >> 3);
        Eea[p] = make_float2(W1[f * 258 + 256], W1[f * 258 + 257]);
    }
}

// ---- node projection, P and Q fused: h read once ----
// PQb[node][p]: p<128 = P (h@W1a^T+b1), p>=128 = Q (h@W1b^T); sigma-permuted
// feature order (position p holds channel (p&7)*16+(p>>3)).
__launch_bounds__(256)
__global__ void node_gemm_f(const float* __restrict__ h,
                            const ushortx8* __restrict__ W1p,
                            const float* __restrict__ b1,
                            unsigned short* __restrict__ PQb) {
    const int w    = threadIdx.x >> 6;
    const int lane = threadIdx.x & 63;
    const int n    = lane & 15;
    const int quad = lane >> 4;
    const int base = (blockIdx.x * 4 + w) * 16;

    int nodeA = base + n;
    if (nodeA >= NNODES) nodeA = NNODES - 1;

    const f32x4 zero = { 0.f, 0.f, 0.f, 0.f };
    f32x4 accP[8], accQ[8];
#pragma unroll
    for (int nt = 0; nt < 8; ++nt) { accP[nt] = zero; accQ[nt] = zero; }

#pragma unroll
    for (int kc = 0; kc < 4; ++kc) {
        const float* p = h + (long)nodeA * HID + kc * 32 + quad * 8;
        float4 lo = *(const float4*)p;
        float4 hi = *(const float4*)(p + 4);
        ushortx8 uu;
        uu[0] = f2bf(lo.x); uu[1] = f2bf(lo.y); uu[2] = f2bf(lo.z); uu[3] = f2bf(lo.w);
        uu[4] = f2bf(hi.x); uu[5] = f2bf(hi.y); uu[6] = f2bf(hi.z); uu[7] = f2bf(hi.w);
        bf16x8 af = __builtin_bit_cast(bf16x8, uu);
#pragma unroll
        for (int nt = 0; nt < 8; ++nt) {
            bf16x8 bP = __builtin_bit_cast(bf16x8, W1p[(kc * 8 + nt) * 64 + lane]);
            bf16x8 bQ = __builtin_bit_cast(bf16x8, W1p[((4 + kc) * 8 + nt) * 64 + lane]);
            accP[nt] = __builtin_amdgcn_mfma_f32_16x16x32_bf16(af, bP, accP[nt], 0, 0, 0);
            accQ[nt] = __builtin_amdgcn_mfma_f32_16x16x32_bf16(af, bQ, accQ[nt], 0, 0, 0);
        }
    }

    float b1v[8];
#pragma unroll
    for (int nt = 0; nt < 8; ++nt) b1v[nt] = b1[nt * 16 + n];

#pragma unroll
    for (int r = 0; r < 4; ++r) {
        int node = base + quad * 4 + r;
        if (node < NNODES) {
            ushortx8 uP, uQ;
#pragma unroll
            for (int nt = 0; nt < 8; ++nt) {
                uP[nt] = f2bf(accP[nt][r] + b1v[nt]);   // stored at p = n*8+nt
                uQ[nt] = f2bf(accQ[nt][r]);
            }
            *(ushortx8*)(PQb + (long)node * 256 + n * 8) = uP;
            *(ushortx8*)(PQb + (long)node * 256 + 128 + n * 8) = uQ;
        }
    }
}

// ---- pipelined edge kernel: T=2 tiles/wave, depth-1 PQ prefetch, NO vgpr cap ----
__launch_bounds__(256)
__global__ void edge16p2(const unsigned short* __restrict__ PQb,
                         const int* __restrict__ ei,
                         const float* __restrict__ cdiff,
                         const float2* __restrict__ eattr,
                         const ushortx8* __restrict__ W2p,
                         const float4* __restrict__ Eea4,
                         const float2* __restrict__ W3b2,
                         float* __restrict__ out) {
    constexpr int T = 2;
    const int lane = threadIdx.x & 63;
    const int n    = lane & 15;
    const int quad = lane >> 4;
    const int base = ((blockIdx.x * 4) + (threadIdx.x >> 6)) * (16 * T);

    int ri[T], ci[T];
    float2 ea[T];
    ushortx8 pf[T][4], qf[T][4];

    auto loadIdx = [&](int t) {
        int el = base + t * 16 + n;
        ri[t] = ei[el];
        ci[t] = ei[E_EDGES + el];
        ea[t] = eattr[el];
    };
    auto loadPQ = [&](int t) {
        const unsigned short* Pb = PQb + (long)ri[t] * 256 + quad * 8;
        const unsigned short* Qb = PQb + (long)ci[t] * 256 + 128 + quad * 8;
#pragma unroll
        for (int kc = 0; kc < 4; ++kc) {
            pf[t][kc] = *(const ushortx8*)(Pb + kc * 32);
            qf[t][kc] = *(const ushortx8*)(Qb + kc * 32);
        }
    };

    loadIdx(0);
    loadPQ(0);
    loadIdx(1);

#pragma unroll
    for (int t = 0; t < T; ++t) {
        if (t + 1 < T) loadPQ(t + 1);
        // ALU/MFMA may cross, VMEM may not: keep prefetch issued above compute.
        __builtin_amdgcn_sched_barrier(0x9);

        float c0 = 0.f, c1 = 0.f, c2 = 0.f;
        if (lane < 16) {
            long e2 = base + t * 16 + lane;
            c0 = cdiff[3 * e2 + 0];
            c1 = cdiff[3 * e2 + 1];
            c2 = cdiff[3 * e2 + 2];
        }

        ushortx8 u[4];
#pragma unroll
        for (int kc = 0; kc < 4; ++kc) {
            float4 ef[4];
#pragma unroll
            for (int q2 = 0; q2 < 4; ++q2) ef[q2] = Eea4[kc * 16 + quad * 4 + q2];
#pragma unroll
            for (int j = 0; j < 8; ++j) {
                float ex = (j & 1) ? ef[j >> 1].z : ef[j >> 1].x;
                float ey = (j & 1) ? ef[j >> 1].w : ef[j >> 1].y;
                float v = bf2f(pf[t][kc][j]) + bf2f(qf[t][kc][j]) + ea[t].x * ex + ea[t].y * ey;
                u[kc][j] = f2bf_fast(silu_fast(v));
            }
        }

        const f32x4 zero = { 0.f, 0.f, 0.f, 0.f };
        f32x4 acc[8];
#pragma unroll
        for (int nt = 0; nt < 8; ++nt) acc[nt] = zero;
#pragma unroll
        for (int kc = 0; kc < 4; ++kc) {
            bf16x8 af = __builtin_bit_cast(bf16x8, u[kc]);
#pragma unroll
            for (int nt = 0; nt < 8; ++nt) {
                bf16x8 bf = __builtin_bit_cast(bf16x8, W2p[(kc * 8 + nt) * 64 + lane]);
                acc[nt] = __builtin_amdgcn_mfma_f32_16x16x32_bf16(af, bf, acc[nt], 0, 0, 0);
            }
        }

        float part[4] = { 0.f, 0.f, 0.f, 0.f };
#pragma unroll
        for (int nt = 0; nt < 8; ++nt) {
            float2 wb = W3b2[nt * 16 + n];   // {W3, b2}
#pragma unroll
            for (int r = 0; r < 4; ++r)
                part[r] += silu_fast(acc[nt][r] + wb.y) * wb.x;
        }
#pragma unroll
        for (int mask = 1; mask < 16; mask <<= 1)
#pragma unroll
            for (int r = 0; r < 4; ++r)
                part[r] += __shfl_xor(part[r], mask, 64);

        float s = 0.f;
#pragma unroll
        for (int r = 0; r < 4; ++r) {
            float t2 = __shfl(part[r], ((lane & 15) >> 2) * 16, 64);
            if ((lane & 3) == r) s = t2;
        }

        if (lane < 16) {
            float ex2 = __expf(2.0f * s);
            float tt = (1.0f - 2.0f * __builtin_amdgcn_rcpf(ex2 + 1.0f)) * 0.15f; // tanh*0.15
            int r = ri[t];   // lane<16: n == lane
            atomicAdd(&out[r * 3 + 0], c0 * tt);
            atomicAdd(&out[r * 3 + 1], c1 * tt);
            atomicAdd(&out[r * 3 + 2], c2 * tt);
        }
    }
}

// ---- fallback (ws too small): round-5 validated ----
__launch_bounds__(256)
__global__ void edge_fb(const float* __restrict__ h, const int* __restrict__ ei,
                        const float* __restrict__ cdiff, const float* __restrict__ eattr,
                        const ushortx8* __restrict__ W1p, const ushortx8* __restrict__ W2p,
                        const float4* __restrict__ Wext, const float* __restrict__ W3,
                        float* __restrict__ out) {
    __shared__ __align__(16) unsigned short x1[4][32][136];
    __shared__ int   rowi[4][32];
    __shared__ int   coli[4][32];
    __shared__ float ea0[4][32];
    __shared__ float ea1[4][32];
    __shared__ float sbuf[4][32];

    const int w = threadIdx.x >> 6, lane = threadIdx.x & 63;
    const int n = lane & 15, quad = lane >> 4;
    const int ebase = (blockIdx.x * 4 + w) * 32;

    if (lane < 32) {
        int e = ebase + lane;
        rowi[w][lane] = ei[e];
        coli[w][lane] = ei[E_EDGES + e];
        const float2 ea = *(const float2*)(eattr + 2 * (long)e);
        ea0[w][lane] = ea.x; ea1[w][lane] = ea.y;
    }
    __syncthreads();

    int nodeR[2] = { rowi[w][n], rowi[w][16 + n] };
    int nodeC[2] = { coli[w][n], coli[w][16 + n] };

    const f32x4 zero = { 0.f, 0.f, 0.f, 0.f };
    f32x4 acc[2][8];
#pragma unroll
    for (int mt = 0; mt < 2; ++mt)
#pragma unroll
        for (int nt = 0; nt < 8; ++nt) acc[mt][nt] = zero;

#pragma unroll
    for (int kc = 0; kc < 8; ++kc) {
        bf16x8 afrag[2];
#pragma unroll
        for (int mt = 0; mt < 2; ++mt) {
            int node = (kc < 4) ? nodeR[mt] : nodeC[mt];
            const float* p = h + (long)node * HID + (kc & 3) * 32 + quad * 8;
            float4 lo = *(const float4*)p;
            float4 hi = *(const float4*)(p + 4);
            ushortx8 u;
            u[0] = f2bf(lo.x); u[1] = f2bf(lo.y); u[2] = f2bf(lo.z); u[3] = f2bf(lo.w);
            u[4] = f2bf(hi.x); u[5] = f2bf(hi.y); u[6] = f2bf(hi.z); u[7] = f2bf(hi.w);
            afrag[mt] = __builtin_bit_cast(bf16x8, u);
        }
#pragma unroll
        for (int nt = 0; nt < 8; ++nt) {
            bf16x8 bfrag = __builtin_bit_cast(bf16x8, W1p[(kc * 8 + nt) * 64 + lane]);
            acc[0][nt] = __builtin_amdgcn_mfma_f32_16x16x32_bf16(afrag[0], bfrag, acc[0][nt], 0, 0, 0);
            acc[1][nt] = __builtin_amdgcn_mfma_f32_16x16x32_bf16(afrag[1], bfrag, acc[1][nt], 0, 0, 0);
        }
    }

    float b2v[8];
    {
        float4 wx[8];
#pragma unroll
        for (int nt = 0; nt < 8; ++nt) wx[nt] = Wext[nt * 16 + n];
#pragma unroll
        for (int nt = 0; nt < 8; ++nt) b2v[nt] = wx[nt].w;
#pragma unroll
        for (int mt = 0; mt < 2; ++mt) {
#pragma unroll
            for (int r = 0; r < 4; ++r) {
                int m = mt * 16 + quad * 4 + r;
                float a0 = ea0[w][m], a1 = ea1[w][m];
                ushortx8 u;
#pragma unroll
                for (int nt = 0; nt < 8; ++nt) {
                    float v = acc[mt][nt][r] + wx[nt].z + a0 * wx[nt].x + a1 * wx[nt].y;
                    u[nt] = f2bf(silu_fast(v));
                }
                *(ushortx8*)&x1[w][m][n * 8] = u;
            }
        }
    }
    __syncthreads();

#pragma unroll
    for (int mt = 0; mt < 2; ++mt)
#pragma unroll
        for (int nt = 0; nt < 8; ++nt) acc[mt][nt] = zero;

#pragma unroll
    for (int kc = 0; kc < 4; ++kc) {
        bf16x8 afrag[2];
#pragma unroll
        for (int mt = 0; mt < 2; ++mt)
            afrag[mt] = __builtin_bit_cast(bf16x8, *(const ushortx8*)&x1[w][mt * 16 + n][kc * 32 + quad * 8]);
#pragma unroll
        for (int nt = 0; nt < 8; ++nt) {
            bf16x8 bfrag = __builtin_bit_cast(bf16x8, W2p[(kc * 8 + nt) * 64 + lane]);
            acc[0][nt] = __builtin_amdgcn_mfma_f32_16x16x32_bf16(afrag[0], bfrag, acc[0][nt], 0, 0, 0);
            acc[1][nt] = __builtin_amdgcn_mfma_f32_16x16x32_bf16(afrag[1], bfrag, acc[1][nt], 0, 0, 0);
        }
    }

    float part[2][4] = { {0.f,0.f,0.f,0.f}, {0.f,0.f,0.f,0.f} };
#pragma unroll
    for (int nt = 0; nt < 8; ++nt) {
        float w3 = W3[nt * 16 + n];
#pragma unroll
        for (int mt = 0; mt < 2; ++mt)
#pragma unroll
            for (int r = 0; r < 4; ++r)
                part[mt][r] += silu_fast(acc[mt][nt][r] + b2v[nt]) * w3;
    }
#pragma unroll
    for (int mask = 1; mask < 16; mask <<= 1)
#pragma unroll
        for (int mt = 0; mt < 2; ++mt)
#pragma unroll
            for (int r = 0; r < 4; ++r)
                part[mt][r] += __shfl_xor(part[mt][r], mask, 64);

    if (n == 0) {
#pragma unroll
        for (int mt = 0; mt < 2; ++mt)
#pragma unroll
            for (int r = 0; r < 4; ++r)
                sbuf[w][mt * 16 + quad * 4 + r] = part[mt][r];
    }
    __syncthreads();

    if (lane < 32) {
        int e = ebase + lane;
        float s = sbuf[w][lane];
        float ex = __expf(2.0f * s);
        float t = (1.0f - 2.0f * __builtin_amdgcn_rcpf(ex + 1.0f)) * 0.15f;
        float c0 = cdiff[3 * (long)e + 0];
        float c1 = cdiff[3 * (long)e + 1];
        float c2 = cdiff[3 * (long)e + 2];
        int r = rowi[w][lane];
        atomicAdd(&out[r * 3 + 0], c0 * t);
        atomicAdd(&out[r * 3 + 1], c1 * t);
        atomicAdd(&out[r * 3 + 2], c2 * t);
    }
}

extern "C" void kernel_launch(void* const* d_in, const int* in_sizes, int n_in,
                              void* d_out, int out_size, void* d_ws, size_t ws_size,
                              hipStream_t stream) {
    const float* h     = (const float*)d_in[0];
    const float* coord = (const float*)d_in[1];
    const int*   ei    = (const int*)d_in[2];
    const float* cdiff = (const float*)d_in[3];
    const float* eattr = (const float*)d_in[4];
    const float* W1    = (const float*)d_in[5];
    const float* b1    = (const float*)d_in[6];
    const float* W2    = (const float*)d_in[7];
    const float* b2    = (const float*)d_in[8];
    const float* W3    = (const float*)d_in[9];
    float* out = (float*)d_out;

    char* ws = (char*)d_ws;
    unsigned short* W1p  = (unsigned short*)ws;                  // 65536 B
    unsigned short* W2p  = (unsigned short*)(ws + 65536);        // 32768 B
    float4*         Wext = (float4*)(ws + 98304);                // 2048 B
    float2*         W3b2 = (float2*)(ws + 100352);               // 1024 B
    float2*         Eea  = (float2*)(ws + 101376);               // 1024 B
    unsigned short* PQb  = (unsigned short*)(ws + 102400);       // 25.6 MB
    const size_t need_full = 102400ull + 25600000ull;

    prep<<<(3 * NNODES + 255) / 256, 256, 0, stream>>>(W1, b1, W2, b2, W3, coord, out,
                                                       W1p, W2p, Wext, W3b2, Eea);

    if (ws_size >= need_full) {
        node_gemm_f<<<(NNODES + 63) / 64, 256, 0, stream>>>(h, (const ushortx8*)W1p, b1, PQb);
        edge16p2<<<E_EDGES / 128, 256, 0, stream>>>(PQb, ei, cdiff, (const float2*)eattr,
                                                    (const ushortx8*)W2p, (const float4*)Eea,
                                                    (const float2*)W3b2, out);
    } else {
        edge_fb<<<E_EDGES / 128, 256, 0, stream>>>(h, ei, cdiff, eattr,
                                                   (const ushortx8*)W1p, (const ushortx8*)W2p,
                                                   (const float4*)Wext, W3, out);
    }
}